// Round 8
// baseline (1755.403 us; speedup 1.0000x reference)
//
#include <hip/hip_runtime.h>
#include <cstdint>

#define DD 1024
#define TT 1024
#define BB 4
#define HH 16
#define EE 8
#define NTOK 4096
#define CAPS 1024

using f16 = _Float16;
using f16x8 = __attribute__((ext_vector_type(8))) _Float16;
using f16x4 = __attribute__((ext_vector_type(4))) _Float16;
using f32x4 = __attribute__((ext_vector_type(4))) float;

#define MFMA16(a, b, c) __builtin_amdgcn_mfma_f32_16x16x32_f16(a, b, c, 0, 0, 0)

__device__ __forceinline__ void gload16(const void* g, void* l) {
  __builtin_amdgcn_global_load_lds((const __attribute__((address_space(1))) unsigned int*)g,
                                   (__attribute__((address_space(3))) unsigned int*)l, 16, 0, 0);
}

__device__ __forceinline__ void split2(float v, f16& h, f16& lo) {
  h = (f16)v;
  lo = (f16)((v - (float)h) * 2048.0f);
}

__device__ __forceinline__ void split_store(f16* ph, f16* pl, float v) {
  f16 h = (f16)v;
  *ph = h;
  *pl = (f16)((v - (float)h) * 2048.0f);
}

// ---------- transpose + split f32 (R,C) -> f16 hi/lo (C,R); LO=false writes hi only ----------
template<bool LO>
__launch_bounds__(256)
__global__ void splitT_k(const float* __restrict__ src, f16* __restrict__ dh, f16* __restrict__ dl,
                         int R, int C, long sSrc, long sDst) {
  __shared__ float tile[64][65];
  long z = blockIdx.z;
  src += z * sSrc; dh += z * sDst; dl += z * sDst;
  int c0 = blockIdx.x * 64, r0 = blockIdx.y * 64;
  int tid = threadIdx.x;
  int lrow = tid >> 2, lc = (tid & 3) * 16;
  const float* sp = src + (long)(r0 + lrow) * C + c0 + lc;
  #pragma unroll
  for (int j = 0; j < 4; ++j) {
    float4 v = *(const float4*)(sp + j * 4);
    tile[lrow][lc + j * 4 + 0] = v.x;
    tile[lrow][lc + j * 4 + 1] = v.y;
    tile[lrow][lc + j * 4 + 2] = v.z;
    tile[lrow][lc + j * 4 + 3] = v.w;
  }
  __syncthreads();
  int oc = tid >> 2, orr = (tid & 3) * 16;
  f16x8 h0, h1, l0, l1;
  #pragma unroll
  for (int j = 0; j < 8; ++j) {
    float v0 = tile[orr + j][oc], v1 = tile[orr + 8 + j][oc];
    h0[j] = (f16)v0; h1[j] = (f16)v1;
    if (LO) {
      l0[j] = (f16)((v0 - (float)h0[j]) * 2048.0f);
      l1[j] = (f16)((v1 - (float)h1[j]) * 2048.0f);
    }
  }
  long ob = (long)(c0 + oc) * R + r0 + orr;
  *(f16x8*)(dh + ob) = h0;
  *(f16x8*)(dh + ob + 8) = h1;
  if (LO) {
    *(f16x8*)(dl + ob) = l0;
    *(f16x8*)(dl + ob + 8) = l1;
  }
}

// ---------- LayerNorm -> f16 split (+optional fused f32 gate softmax) ----------
template<bool GATE>
__launch_bounds__(256)
__global__ void ln_k(const float* __restrict__ x, const float* __restrict__ g, const float* __restrict__ b,
                     f16* __restrict__ oh, f16* __restrict__ ol,
                     const float* __restrict__ gw, float* __restrict__ gates) {
  int row = blockIdx.x, tid = threadIdx.x;
  int lane = tid & 63, wid = tid >> 6;
  __shared__ float red[4];
  __shared__ float pg[4][8];
  __shared__ float logits[8];
  const float* xr = x + (long)row * DD;
  int col = tid * 4;
  float4 v = *(const float4*)(xr + col);
  float s = v.x + v.y + v.z + v.w;
  #pragma unroll
  for (int off = 32; off >= 1; off >>= 1) s += __shfl_down(s, off);
  if (lane == 0) red[wid] = s;
  __syncthreads();
  float mu = (red[0] + red[1] + red[2] + red[3]) * (1.0f / DD);
  float d0 = v.x - mu, d1 = v.y - mu, d2 = v.z - mu, d3 = v.w - mu;
  float sq = d0 * d0 + d1 * d1 + d2 * d2 + d3 * d3;
  __syncthreads();
  #pragma unroll
  for (int off = 32; off >= 1; off >>= 1) sq += __shfl_down(sq, off);
  if (lane == 0) red[wid] = sq;
  __syncthreads();
  float var = (red[0] + red[1] + red[2] + red[3]) * (1.0f / DD);
  float rstd = rsqrtf(var + 1e-5f);
  float xv[4];
  xv[0] = d0 * rstd * g[col] + b[col];
  xv[1] = d1 * rstd * g[col + 1] + b[col + 1];
  xv[2] = d2 * rstd * g[col + 2] + b[col + 2];
  xv[3] = d3 * rstd * g[col + 3] + b[col + 3];
  f16x4 hv, lv;
  #pragma unroll
  for (int j = 0; j < 4; ++j) { f16 h, lo; split2(xv[j], h, lo); hv[j] = h; lv[j] = lo; }
  *(f16x4*)(oh + (long)row * DD + col) = hv;
  *(f16x4*)(ol + (long)row * DD + col) = lv;
  if (GATE) {
    float part[8];
    #pragma unroll
    for (int e = 0; e < 8; ++e) part[e] = 0.0f;
    #pragma unroll
    for (int j = 0; j < 4; ++j) {
      const float* gwr = gw + (long)(col + j) * 8;
      #pragma unroll
      for (int e = 0; e < 8; ++e) part[e] += xv[j] * gwr[e];
    }
    #pragma unroll
    for (int off = 32; off >= 1; off >>= 1) {
      #pragma unroll
      for (int e = 0; e < 8; ++e) part[e] += __shfl_down(part[e], off);
    }
    if (lane == 0) {
      #pragma unroll
      for (int e = 0; e < 8; ++e) pg[wid][e] = part[e];
    }
    __syncthreads();
    if (tid < 8) logits[tid] = pg[0][tid] + pg[1][tid] + pg[2][tid] + pg[3][tid];
    __syncthreads();
    if (tid < 8) {
      float mx = logits[0];
      #pragma unroll
      for (int e2 = 1; e2 < 8; ++e2) mx = fmaxf(mx, logits[e2]);
      float den = 0.0f;
      #pragma unroll
      for (int e2 = 0; e2 < 8; ++e2) den += expf(logits[e2] - mx);
      gates[(long)row * 8 + tid] = expf(logits[tid] - mx) / den;
    }
  }
}

// ---------- rope tables ----------
__global__ void sincos_k(float* st, float* ct) {
  int i = blockIdx.x * 256 + threadIdx.x;
  if (i >= TT * 32) return;
  int t = i >> 5, f = i & 31;
  float inv = powf(10000.0f, -(float)f * (1.0f / 32.0f));
  float ang = (float)t * inv;
  st[i] = sinf(ang);
  ct[i] = cosf(ang);
}

// ---------- flash attention v3: direct-from-L2 K/V (no LDS staging, no barriers) ----------
// 4 waves x 32 q-rows, per-wave early exit; P relay via wave-private swizzled LDS.
__launch_bounds__(256, 3)
__global__ void attn_k(const f16* __restrict__ qh, const f16* __restrict__ ql,
                       const f16* __restrict__ kh, const f16* __restrict__ kl,
                       const f16* __restrict__ vth, const f16* __restrict__ vtl,
                       f16* __restrict__ oh_out, f16* __restrict__ ol_out) {
  __shared__ __align__(16) f16 Pw[4][2][2048];  // [wave][hi/lo][32*64]
  int bx = blockIdx.x;
  int bh = bx & 63;
  int qt = (int)((0x31204657u >> ((bx >> 6) << 2)) & 7u);  // pair big+small qt per CU
  int tid = threadIdx.x;
  int wid = tid >> 6, lane = tid & 63;
  int lr = lane & 15, lg = lane >> 4;
  long bhT = (long)bh * TT;
  int qrow0 = qt * 128 + wid * 32;
  int qend = qrow0 + 32;

  f16x8 qfh[2][2], qfl[2][2];
  #pragma unroll
  for (int qi = 0; qi < 2; ++qi) {
    long qoff = (bhT + qrow0 + qi * 16 + lr) * 64 + lg * 8;
    qfh[qi][0] = *(const f16x8*)(qh + qoff);
    qfh[qi][1] = *(const f16x8*)(qh + qoff + 32);
    qfl[qi][0] = *(const f16x8*)(ql + qoff);
    qfl[qi][1] = *(const f16x8*)(ql + qoff + 32);
  }

  f32x4 o_hi[2][4], o_md[2][4];
  #pragma unroll
  for (int qi = 0; qi < 2; ++qi)
    #pragma unroll
    for (int dj = 0; dj < 4; ++dj) {
      o_hi[qi][dj] = {0.f, 0.f, 0.f, 0.f};
      o_md[qi][dj] = {0.f, 0.f, 0.f, 0.f};
    }
  float m[2][4], lsum[2][4];
  #pragma unroll
  for (int qi = 0; qi < 2; ++qi)
    #pragma unroll
    for (int r = 0; r < 4; ++r) { m[qi][r] = -1e30f; lsum[qi][r] = 0.0f; }

  int rsw = lr & 7;
  int c0 = ((lg ^ rsw) << 3), c1 = (((4 | lg) ^ rsw) << 3);
  f16* Ph = Pw[wid][0];
  f16* Pl = Pw[wid][1];

  const f16* kbh = kh + bhT * 64;
  const f16* kbl = kl + bhT * 64;
  const f16* vbh = vth + (long)bh * 64 * TT;
  const f16* vbl = vtl + (long)bh * 64 * TT;

  int ntw = (qend + 63) >> 6;  // per-wave tile count (early exit)
  for (int kb = 0; kb < ntw; ++kb) {
    int kv0 = kb * 64;
    // ---- QK^T: K fragments direct from global (L2-resident) ----
    f32x4 s[2][4];
    #pragma unroll
    for (int kj = 0; kj < 4; ++kj) {
      long ko = (long)(kv0 + kj * 16 + lr) * 64 + lg * 8;
      f16x8 kfh0 = *(const f16x8*)(kbh + ko);
      f16x8 kfh1 = *(const f16x8*)(kbh + ko + 32);
      f16x8 kfl0 = *(const f16x8*)(kbl + ko);
      f16x8 kfl1 = *(const f16x8*)(kbl + ko + 32);
      #pragma unroll
      for (int qi = 0; qi < 2; ++qi) {
        f32x4 a = {0.f, 0.f, 0.f, 0.f};
        a = MFMA16(qfh[qi][0], kfh0, a);
        a = MFMA16(qfh[qi][1], kfh1, a);
        a = a * 2048.0f;
        a = MFMA16(qfh[qi][0], kfl0, a);
        a = MFMA16(qfh[qi][1], kfl1, a);
        a = MFMA16(qfl[qi][0], kfh0, a);
        a = MFMA16(qfl[qi][1], kfh1, a);
        s[qi][kj] = a;
      }
    }
    const float ss = 0.125f / 2048.0f;
    bool needmask = (kv0 + 64 > qrow0);
    float rm[2][4];
    #pragma unroll
    for (int qi = 0; qi < 2; ++qi)
      #pragma unroll
      for (int r = 0; r < 4; ++r) {
        int qrow = qrow0 + qi * 16 + lg * 4 + r;
        float mx = -1e30f;
        #pragma unroll
        for (int kj = 0; kj < 4; ++kj) {
          float v = s[qi][kj][r] * ss;
          if (needmask && (kv0 + kj * 16 + lr > qrow)) v = -1e9f;
          s[qi][kj][r] = v;
          mx = fmaxf(mx, v);
        }
        rm[qi][r] = mx;
      }
    #pragma unroll
    for (int off = 1; off < 16; off <<= 1)
      #pragma unroll
      for (int qi = 0; qi < 2; ++qi)
        #pragma unroll
        for (int r = 0; r < 4; ++r) rm[qi][r] = fmaxf(rm[qi][r], __shfl_xor(rm[qi][r], off));
    float alpha[2][4], rs[2][4];
    #pragma unroll
    for (int qi = 0; qi < 2; ++qi)
      #pragma unroll
      for (int r = 0; r < 4; ++r) {
        float mn = fmaxf(m[qi][r], rm[qi][r]);
        alpha[qi][r] = __expf(m[qi][r] - mn);
        m[qi][r] = mn;
        rs[qi][r] = 0.0f;
      }
    #pragma unroll
    for (int qi = 0; qi < 2; ++qi)
      #pragma unroll
      for (int kj = 0; kj < 4; ++kj)
        #pragma unroll
        for (int r = 0; r < 4; ++r) {
          float p = __expf(s[qi][kj][r] - m[qi][r]);
          rs[qi][r] += p;
          int prow = qi * 16 + lg * 4 + r;
          int pcol = kj * 16 + lr;
          int idx = prow * 64 + (((pcol >> 3) ^ (prow & 7)) << 3) + (pcol & 7);
          f16 hv = (f16)p;
          Ph[idx] = hv;
          Pl[idx] = (f16)((p - (float)hv) * 2048.0f);
        }
    #pragma unroll
    for (int off = 1; off < 16; off <<= 1)
      #pragma unroll
      for (int qi = 0; qi < 2; ++qi)
        #pragma unroll
        for (int r = 0; r < 4; ++r) rs[qi][r] += __shfl_xor(rs[qi][r], off);
    #pragma unroll
    for (int qi = 0; qi < 2; ++qi)
      #pragma unroll
      for (int r = 0; r < 4; ++r) lsum[qi][r] = lsum[qi][r] * alpha[qi][r] + rs[qi][r];
    #pragma unroll
    for (int qi = 0; qi < 2; ++qi)
      #pragma unroll
      for (int dj = 0; dj < 4; ++dj)
        #pragma unroll
        for (int r = 0; r < 4; ++r) {
          o_hi[qi][dj][r] *= alpha[qi][r];
          o_md[qi][dj][r] *= alpha[qi][r];
        }
    f16x8 pah[2][2], pal[2][2];
    #pragma unroll
    for (int qi = 0; qi < 2; ++qi) {
      int pr = (qi * 16 + lr) * 64;
      pah[qi][0] = *(const f16x8*)(Ph + pr + c0);
      pah[qi][1] = *(const f16x8*)(Ph + pr + c1);
      pal[qi][0] = *(const f16x8*)(Pl + pr + c0);
      pal[qi][1] = *(const f16x8*)(Pl + pr + c1);
    }
    // ---- PV: V fragments direct from global (L2-resident) ----
    #pragma unroll
    for (int dj = 0; dj < 4; ++dj) {
      long vo = (long)(dj * 16 + lr) * TT + kv0 + lg * 8;
      f16x8 vh0 = *(const f16x8*)(vbh + vo);
      f16x8 vh1 = *(const f16x8*)(vbh + vo + 32);
      f16x8 vl0 = *(const f16x8*)(vbl + vo);
      f16x8 vl1 = *(const f16x8*)(vbl + vo + 32);
      #pragma unroll
      for (int qi = 0; qi < 2; ++qi) {
        o_hi[qi][dj] = MFMA16(pah[qi][0], vh0, o_hi[qi][dj]);
        o_hi[qi][dj] = MFMA16(pah[qi][1], vh1, o_hi[qi][dj]);
        o_md[qi][dj] = MFMA16(pah[qi][0], vl0, o_md[qi][dj]);
        o_md[qi][dj] = MFMA16(pah[qi][1], vl1, o_md[qi][dj]);
        o_md[qi][dj] = MFMA16(pal[qi][0], vh0, o_md[qi][dj]);
        o_md[qi][dj] = MFMA16(pal[qi][1], vh1, o_md[qi][dj]);
      }
    }
  }

  int b = bh >> 4, hh = bh & 15;
  #pragma unroll
  for (int qi = 0; qi < 2; ++qi)
    #pragma unroll
    for (int r = 0; r < 4; ++r) {
      float invl = 1.0f / lsum[qi][r];
      int qrow = qrow0 + qi * 16 + lg * 4 + r;
      long obase = ((long)(b * TT + qrow)) * DD + hh * 64 + lr;
      #pragma unroll
      for (int dj = 0; dj < 4; ++dj) {
        float val = (o_hi[qi][dj][r] + o_md[qi][dj][r] * (1.0f / 2048.0f)) * invl;
        f16 hv = (f16)val;
        oh_out[obase + dj * 16] = hv;
        ol_out[obase + dj * 16] = (f16)((val - (float)hv) * 2048.0f);
      }
    }
}

// ---------- fused split-2 f16 GEMM: one K-loop (R3 structure) + XCD-aware grid ----------
// smode 0: 3D grid (bn,bm,z). smode 1: 1D grid, id&7 = expert(z)=XCD, 8x8 supertiles.
// smode 2: 1D grid, bijective chunked XCD swizzle (z=0), 8x8 supertiles, needs M%1024==0.
// EPI 0: outF=v. 1: outF=v+resid. 2: split(gelu(v+bias))->outH/L. 3: outF=v+bias.
// EPI 4: fused qkv rope epilogue: resid=sin table, bias=cos table; q->(q4h,q4l),
//        k->(k4h,k4l) at (b,h,t,64); v->(outH,outL) transposed (b,h,64,t).
template<int EPI, bool SPLIT>
__launch_bounds__(256, 2)
__global__ void gemmF(const f16* __restrict__ Ah, const f16* __restrict__ Al, long sA,
                      const f16* __restrict__ Bh, const f16* __restrict__ Bl, long sB,
                      int M, int N, int K, int smode,
                      float* __restrict__ outF, long sOutF,
                      const float* __restrict__ resid,
                      const float* __restrict__ bias, long sBias,
                      f16* __restrict__ outH, f16* __restrict__ outL, long sOutH,
                      f16* __restrict__ q4h, f16* __restrict__ q4l,
                      f16* __restrict__ k4h, f16* __restrict__ k4l) {
  __shared__ __align__(16) f16 pool[(SPLIT ? 4 : 2) * 128 * 64];
  f16* AsH = pool;
  f16* BsH = pool + 8192;
  f16* AsL = SPLIT ? pool + 16384 : pool;
  f16* BsL = SPLIT ? pool + 24576 : pool;

  int bm, bn, z;
  if (smode == 0) {
    bn = blockIdx.x; bm = blockIdx.y; z = blockIdx.z;
  } else {
    int id = blockIdx.x;
    int logical;
    if (smode == 1) { z = id & 7; logical = id >> 3; }
    else { z = 0; int cpx = (int)(gridDim.x >> 3); logical = (id & 7) * cpx + (id >> 3); }
    int st = logical >> 6, wi = logical & 63;
    int nstm = (smode == 1) ? 1 : (M >> 10);  // supertile rows = M/128/8
    int stm = st % nstm, stn = st / nstm;
    bm = (stm << 3) | (wi & 7);
    bn = (stn << 3) | (wi >> 3);
  }

  int tid = threadIdx.x;
  int wid = tid >> 6, lane = tid & 63;
  int wm = (wid >> 1) * 64, wn = (wid & 1) * 64;
  int lr = lane & 15, lg = lane >> 4;

  f32x4 aH[4][4], aL[4][4];
  #pragma unroll
  for (int i = 0; i < 4; ++i)
    #pragma unroll
    for (int j = 0; j < 4; ++j) {
      aH[i][j] = {0.f, 0.f, 0.f, 0.f};
      if (SPLIT) aL[i][j] = {0.f, 0.f, 0.f, 0.f};
    }

  int srow = tid >> 3;
  int gcol = (((tid & 7) ^ (srow & 7)) << 3);
  const f16* apH = Ah + (long)z * sA + ((long)(bm * 128 + srow)) * K + gcol;
  const f16* bpH = Bh + (long)z * sB + ((long)(bn * 128 + srow)) * K + gcol;
  const f16* apL = nullptr; const f16* bpL = nullptr;
  if (SPLIT) {
    apL = Al + (long)z * sA + ((long)(bm * 128 + srow)) * K + gcol;
    bpL = Bl + (long)z * sB + ((long)(bn * 128 + srow)) * K + gcol;
  }
  int tid8 = tid * 8;
  int rsw = lr & 7;

  for (int kt = 0; kt < K; kt += 64) {
    #pragma unroll
    for (int r4 = 0; r4 < 4; ++r4) {
      long go = (long)kt + (long)(r4 * 32) * K;
      int lo = tid8 + r4 * 2048;
      gload16(apH + go, AsH + lo);
      gload16(bpH + go, BsH + lo);
      if (SPLIT) {
        gload16(apL + go, AsL + lo);
        gload16(bpL + go, BsL + lo);
      }
    }
    __syncthreads();
    #pragma unroll
    for (int kk2 = 0; kk2 < 2; ++kk2) {
      int sws = (((kk2 << 2) | lg) ^ rsw) << 3;
      f16x8 afH[4], afL[4];
      #pragma unroll
      for (int i = 0; i < 4; ++i) {
        int ro = (wm + i * 16 + lr) * 64 + sws;
        afH[i] = *(const f16x8*)(AsH + ro);
        if (SPLIT) afL[i] = *(const f16x8*)(AsL + ro);
      }
      #pragma unroll
      for (int j = 0; j < 4; ++j) {
        int ro = (wn + j * 16 + lr) * 64 + sws;
        f16x8 bH = *(const f16x8*)(BsH + ro);
        #pragma unroll
        for (int i = 0; i < 4; ++i) aH[i][j] = MFMA16(afH[i], bH, aH[i][j]);
        if (SPLIT) {
          f16x8 bL = *(const f16x8*)(BsL + ro);
          #pragma unroll
          for (int i = 0; i < 4; ++i) {
            aL[i][j] = MFMA16(afH[i], bL, aL[i][j]);
            aL[i][j] = MFMA16(afL[i], bH, aL[i][j]);
          }
        }
      }
    }
    __syncthreads();
  }

  if (EPI == 4) {
    int c64 = (bn * 128 + wn) >> 6;
    int type = c64 % 3, hd = c64 / 3;   // 0=q 1=k 2=v
    const float* stab = resid;
    const float* ctab = bias;
    #pragma unroll
    for (int i = 0; i < 4; ++i) {
      #pragma unroll
      for (int r = 0; r < 4; ++r) {
        int row = bm * 128 + wm + i * 16 + lg * 4 + r;
        int b = row >> 10, t = row & (TT - 1);
        long bh = (long)(b * HH + hd);
        if (type == 2) {
          #pragma unroll
          for (int j = 0; j < 4; ++j) {
            float v = aH[i][j][r] + aL[i][j][r] * (1.0f / 2048.0f);
            int d = j * 16 + lr;
            long idx = (bh * 64 + d) * TT + t;
            split_store(outH + idx, outL + idx, v);
          }
        } else {
          f16* oh = (type == 0) ? q4h : k4h;
          f16* ol = (type == 0) ? q4l : k4l;
          long obase = (bh * TT + t) * 64;
          #pragma unroll
          for (int j = 0; j < 2; ++j) {
            int half = j * 16 + lr;
            float sa = stab[t * 32 + half], ca = ctab[t * 32 + half];
            float x1 = aH[i][j][r] + aL[i][j][r] * (1.0f / 2048.0f);
            float x2 = aH[i][j + 2][r] + aL[i][j + 2][r] * (1.0f / 2048.0f);
            split_store(oh + obase + half, ol + obase + half, x1 * ca - x2 * sa);
            split_store(oh + obase + half + 32, ol + obase + half + 32, x1 * sa + x2 * ca);
          }
        }
      }
    }
    return;
  }

  #pragma unroll
  for (int i = 0; i < 4; ++i) {
    #pragma unroll
    for (int j = 0; j < 4; ++j) {
      #pragma unroll
      for (int r = 0; r < 4; ++r) {
        int row = bm * 128 + wm + i * 16 + lg * 4 + r;
        int col = bn * 128 + wn + j * 16 + lr;
        float v = aH[i][j][r];
        if (SPLIT) v += aL[i][j][r] * (1.0f / 2048.0f);
        if (EPI == 0) {
          outF[(long)row * N + col] = v;
        } else if (EPI == 1) {
          long idx = (long)row * N + col;
          outF[idx] = v + resid[idx];
        } else if (EPI == 2) {
          float t = v + bias[(long)z * sBias + col];
          float ge = 0.5f * t * (1.0f + erff(t * 0.70710678118f));
          long idx = (long)z * sOutH + (long)row * N + col;
          f16 hv = (f16)ge;
          outH[idx] = hv;
          if (SPLIT) outL[idx] = (f16)((ge - (float)hv) * 2048.0f);
        } else {
          long idx = (long)z * sOutF + (long)row * N + col;
          outF[idx] = v + bias[(long)z * sBias + col];
        }
      }
    }
  }
}

// ---------- routing: top-2 + per-expert capacity scan (exact ref semantics) ----------
__launch_bounds__(512)
__global__ void route_k(const float* __restrict__ gates, int* __restrict__ etok, int* __restrict__ slotof) {
  __shared__ unsigned char lmask[NTOK];
  __shared__ unsigned char ltop[NTOK];
  int tid = threadIdx.x;
  for (int t = tid; t < NTOK; t += 512) {
    const float* gr = gates + (long)t * 8;
    float gv[8];
    #pragma unroll
    for (int e = 0; e < 8; ++e) gv[e] = gr[e];
    int e1 = 0; float bv = gv[0];
    #pragma unroll
    for (int e = 1; e < 8; ++e) if (gv[e] > bv) { bv = gv[e]; e1 = e; }
    int e2 = -1; float bv2 = -1e30f;
    #pragma unroll
    for (int e = 0; e < 8; ++e) if (e != e1 && gv[e] > bv2) { bv2 = gv[e]; e2 = e; }
    lmask[t] = (unsigned char)((1u << e1) | (1u << e2));
    ltop[t] = (unsigned char)(e1 | (e2 << 4));
    slotof[t * 2] = -1;
    slotof[t * 2 + 1] = -1;
  }
  __syncthreads();
  int e = tid >> 6, lane = tid & 63;
  int cnt = 0;
  for (int c = 0; c < NTOK / 64; ++c) {
    int t = c * 64 + lane;
    int bit = (lmask[t] >> e) & 1;
    unsigned long long bal = __ballot(bit);
    int pre = __popcll(bal & ((1ull << lane) - 1ull));
    int slot = cnt + pre;
    if (bit && slot < CAPS) {
      etok[e * CAPS + slot] = t;
      int tp = ltop[t];
      int k = ((tp & 15) == e) ? 0 : 1;
      slotof[t * 2 + k] = (e << 16) | slot;
    }
    cnt += __popcll(bal);
  }
  int kept = cnt < CAPS ? cnt : CAPS;
  for (int s = kept + lane; s < CAPS; s += 64) etok[e * CAPS + s] = 0;
}

// ---------- gather rows for experts ----------
__global__ void gather_k(const int* __restrict__ etok, const f16* __restrict__ xh, const f16* __restrict__ xl,
                         f16* __restrict__ gh, f16* __restrict__ gl) {
  int es = blockIdx.x, tid = threadIdx.x;  // 128 threads
  int tok = etok[es];
  const uint4* s1 = (const uint4*)(xh + (long)tok * DD);
  const uint4* s2 = (const uint4*)(xl + (long)tok * DD);
  ((uint4*)(gh + (long)es * DD))[tid] = s1[tid];
  ((uint4*)(gl + (long)es * DD))[tid] = s2[tid];
}

// ---------- scatter expert outputs back (x += sum gv * out), no atomics ----------
__global__ void scatter_k(const int* __restrict__ slotof, const float* __restrict__ gates,
                          const float* __restrict__ moe, float* __restrict__ x) {
  int t = blockIdx.x, tid = threadIdx.x;  // 256 threads
  int s0 = slotof[t * 2], s1 = slotof[t * 2 + 1];
  float4* xr = (float4*)(x + (long)t * DD);
  float4 v = xr[tid];
  if (s0 >= 0) {
    int e = s0 >> 16, sl = s0 & 0xffff;
    float gv = gates[(long)t * 8 + e];
    float4 mo = ((const float4*)(moe + ((long)e * CAPS + sl) * DD))[tid];
    v.x += gv * mo.x; v.y += gv * mo.y; v.z += gv * mo.z; v.w += gv * mo.w;
  }
  if (s1 >= 0) {
    int e = s1 >> 16, sl = s1 & 0xffff;
    float gv = gates[(long)t * 8 + e];
    float4 mo = ((const float4*)(moe + ((long)e * CAPS + sl) * DD))[tid];
    v.x += gv * mo.x; v.y += gv * mo.y; v.z += gv * mo.z; v.w += gv * mo.w;
  }
  xr[tid] = v;
}

extern "C" void kernel_launch(void* const* d_in, const int* in_sizes, int n_in,
                              void* d_out, int out_size, void* d_ws, size_t ws_size,
                              hipStream_t stream) {
  const float* x_in   = (const float*)d_in[0];
  const float* ln1_g  = (const float*)d_in[1];
  const float* ln1_b  = (const float*)d_in[2];
  const float* qkv_w  = (const float*)d_in[3];
  const float* proj_w = (const float*)d_in[4];
  const float* ln2_g  = (const float*)d_in[5];
  const float* ln2_b  = (const float*)d_in[6];
  const float* gate_w = (const float*)d_in[7];
  const float* w1     = (const float*)d_in[8];
  const float* b1     = (const float*)d_in[9];
  const float* w2     = (const float*)d_in[10];
  const float* b2     = (const float*)d_in[11];
  float* x = (float*)d_out;

  char* p = (char*)d_ws;
  auto alloc = [&](size_t bytes) { char* r = p; p += (bytes + 255) & ~(size_t)255; return (void*)r; };

  f16* Wreg   = (f16*)alloc(134217728);           // weight split region (reused)
  f16* qhB  = (f16*)alloc(4194304ull * 2);
  f16* qlB  = (f16*)alloc(4194304ull * 2);
  f16* khB  = (f16*)alloc(4194304ull * 2);
  f16* klB  = (f16*)alloc(4194304ull * 2);
  f16* vthB = (f16*)alloc(4194304ull * 2);
  f16* vtlB = (f16*)alloc(4194304ull * 2);
  f16* xnh  = (f16*)alloc(4194304ull * 2);
  f16* xnl  = (f16*)alloc(4194304ull * 2);
  f16* atth = (f16*)alloc(4194304ull * 2);
  f16* attl = (f16*)alloc(4194304ull * 2);
  f16* xgh  = (f16*)alloc(8388608ull * 2);
  f16* xgl  = (f16*)alloc(8388608ull * 2);
  f16* hhB  = (f16*)alloc(33554432ull * 2);
  f16* hlB  = (f16*)alloc(33554432ull * 2);
  float* moe = (float*)alloc(8388608ull * 4);
  float* stab = (float*)alloc(32768ull * 4);
  float* ctab = (float*)alloc(32768ull * 4);
  float* gates = (float*)alloc(32768ull * 4);
  int* etok  = (int*)alloc(8192ull * 4);
  int* slotof = (int*)alloc(8192ull * 4);

  f16* qkvTh = Wreg;
  f16* qkvTl = Wreg + 3145728;
  f16* projTh = Wreg + 2 * 3145728;
  f16* projTl = Wreg + 2 * 3145728 + 1048576;
  f16* w1Th = Wreg;
  f16* w1Tl = Wreg + 33554432;
  f16* w2Th = Wreg;
  f16* w2Tl = Wreg + 33554432;

  hipMemcpyAsync(x, x_in, (size_t)NTOK * DD * 4, hipMemcpyDeviceToDevice, stream);
  sincos_k<<<(TT * 32 + 255) / 256, 256, 0, stream>>>(stab, ctab);

  for (int l = 0; l < 2; ++l) {
    // --- attention half ---
    splitT_k<true><<<dim3(3072 / 64, 1024 / 64, 1), 256, 0, stream>>>(
        qkv_w + (long)l * DD * 3072, qkvTh, qkvTl, 1024, 3072, 0, 0);
    splitT_k<true><<<dim3(1024 / 64, 1024 / 64, 1), 256, 0, stream>>>(
        proj_w + (long)l * DD * DD, projTh, projTl, 1024, 1024, 0, 0);
    ln_k<false><<<NTOK, 256, 0, stream>>>(x, ln1_g + l * DD, ln1_b + l * DD, xnh, xnl, nullptr, nullptr);
    gemmF<4, true><<<768, 256, 0, stream>>>(                     // fused qkv+rope, smode 2
        xnh, xnl, 0, qkvTh, qkvTl, 0, 4096, 3072, 1024, 2,
        nullptr, 0, stab, ctab, 0, vthB, vtlB, 0, qhB, qlB, khB, klB);
    attn_k<<<512, 256, 0, stream>>>(qhB, qlB, khB, klB, vthB, vtlB, atth, attl);
    gemmF<1, true><<<256, 256, 0, stream>>>(                     // smode 2 chunked
        atth, attl, 0, projTh, projTl, 0, 4096, 1024, 1024, 2,
        x, 0, x, nullptr, 0, nullptr, nullptr, 0, nullptr, nullptr, nullptr, nullptr);

    // --- MoE half ---
    ln_k<true><<<NTOK, 256, 0, stream>>>(x, ln2_g + l * DD, ln2_b + l * DD, xnh, xnl,
                                         gate_w + (long)l * DD * EE, gates);
    route_k<<<1, 512, 0, stream>>>(gates, etok, slotof);
    gather_k<<<EE * CAPS, 128, 0, stream>>>(etok, xnh, xnl, xgh, xgl);
    if (l == 0) {
      splitT_k<true><<<dim3(4096 / 64, 1024 / 64, EE), 256, 0, stream>>>(
          w1 + (long)l * EE * DD * 4096, w1Th, w1Tl, 1024, 4096, (long)DD * 4096, (long)4096 * DD);
      gemmF<2, true><<<2048, 256, 0, stream>>>(                  // smode 1 expert->XCD
          xgh, xgl, (long)CAPS * DD, w1Th, w1Tl, (long)4096 * DD, 1024, 4096, 1024, 1,
          nullptr, 0, nullptr, b1 + (long)l * EE * 4096, 4096, hhB, hlB, (long)CAPS * 4096,
          nullptr, nullptr, nullptr, nullptr);
      splitT_k<true><<<dim3(1024 / 64, 4096 / 64, EE), 256, 0, stream>>>(
          w2 + (long)l * EE * 4096 * DD, w2Th, w2Tl, 4096, 1024, (long)4096 * DD, (long)DD * 4096);
      gemmF<3, true><<<512, 256, 0, stream>>>(                   // smode 1 expert->XCD
          hhB, hlB, (long)CAPS * 4096, w2Th, w2Tl, (long)DD * 4096, 1024, 1024, 4096, 1,
          moe, (long)CAPS * DD, nullptr, b2 + (long)l * EE * DD, DD, nullptr, nullptr, 0,
          nullptr, nullptr, nullptr, nullptr);
    } else {
      splitT_k<false><<<dim3(4096 / 64, 1024 / 64, EE), 256, 0, stream>>>(
          w1 + (long)l * EE * DD * 4096, w1Th, w1Tl, 1024, 4096, (long)DD * 4096, (long)4096 * DD);
      gemmF<2, false><<<2048, 256, 0, stream>>>(
          xgh, xgl, (long)CAPS * DD, w1Th, w1Tl, (long)4096 * DD, 1024, 4096, 1024, 1,
          nullptr, 0, nullptr, b1 + (long)l * EE * 4096, 4096, hhB, hlB, (long)CAPS * 4096,
          nullptr, nullptr, nullptr, nullptr);
      splitT_k<false><<<dim3(1024 / 64, 4096 / 64, EE), 256, 0, stream>>>(
          w2 + (long)l * EE * 4096 * DD, w2Th, w2Tl, 4096, 1024, (long)4096 * DD, (long)DD * 4096);
      gemmF<3, false><<<512, 256, 0, stream>>>(
          hhB, hlB, (long)CAPS * 4096, w2Th, w2Tl, (long)DD * 4096, 1024, 1024, 4096, 1,
          moe, (long)CAPS * DD, nullptr, b2 + (long)l * EE * DD, DD, nullptr, nullptr, 0,
          nullptr, nullptr, nullptr, nullptr);
    }
    scatter_k<<<NTOK, 256, 0, stream>>>(slotof, gates, moe, x);
  }
  (void)in_sizes; (void)n_in; (void)out_size; (void)ws_size;
}

// Round 9
// 1425.872 us; speedup vs baseline: 1.2311x; 1.2311x over previous
//
#include <hip/hip_runtime.h>
#include <cstdint>

#define DD 1024
#define TT 1024
#define BB 4
#define HH 16
#define EE 8
#define NTOK 4096
#define CAPS 1024

using f16 = _Float16;
using f16x8 = __attribute__((ext_vector_type(8))) _Float16;
using f16x4 = __attribute__((ext_vector_type(4))) _Float16;
using f32x4 = __attribute__((ext_vector_type(4))) float;

#define MFMA16(a, b, c) __builtin_amdgcn_mfma_f32_16x16x32_f16(a, b, c, 0, 0, 0)

__device__ __forceinline__ void gload16(const void* g, void* l) {
  __builtin_amdgcn_global_load_lds((const __attribute__((address_space(1))) unsigned int*)g,
                                   (__attribute__((address_space(3))) unsigned int*)l, 16, 0, 0);
}

__device__ __forceinline__ void split2(float v, f16& h, f16& lo) {
  h = (f16)v;
  lo = (f16)((v - (float)h) * 2048.0f);
}

__device__ __forceinline__ void split_store(f16* ph, f16* pl, float v) {
  f16 h = (f16)v;
  *ph = h;
  *pl = (f16)((v - (float)h) * 2048.0f);
}

// ---------- transpose + split f32 (R,C) -> f16 hi/lo (C,R); LO=false writes hi only ----------
template<bool LO>
__launch_bounds__(256)
__global__ void splitT_k(const float* __restrict__ src, f16* __restrict__ dh, f16* __restrict__ dl,
                         int R, int C, long sSrc, long sDst) {
  __shared__ float tile[64][65];
  long z = blockIdx.z;
  src += z * sSrc; dh += z * sDst; dl += z * sDst;
  int c0 = blockIdx.x * 64, r0 = blockIdx.y * 64;
  int tid = threadIdx.x;
  int lrow = tid >> 2, lc = (tid & 3) * 16;
  const float* sp = src + (long)(r0 + lrow) * C + c0 + lc;
  #pragma unroll
  for (int j = 0; j < 4; ++j) {
    float4 v = *(const float4*)(sp + j * 4);
    tile[lrow][lc + j * 4 + 0] = v.x;
    tile[lrow][lc + j * 4 + 1] = v.y;
    tile[lrow][lc + j * 4 + 2] = v.z;
    tile[lrow][lc + j * 4 + 3] = v.w;
  }
  __syncthreads();
  int oc = tid >> 2, orr = (tid & 3) * 16;
  f16x8 h0, h1, l0, l1;
  #pragma unroll
  for (int j = 0; j < 8; ++j) {
    float v0 = tile[orr + j][oc], v1 = tile[orr + 8 + j][oc];
    h0[j] = (f16)v0; h1[j] = (f16)v1;
    if (LO) {
      l0[j] = (f16)((v0 - (float)h0[j]) * 2048.0f);
      l1[j] = (f16)((v1 - (float)h1[j]) * 2048.0f);
    }
  }
  long ob = (long)(c0 + oc) * R + r0 + orr;
  *(f16x8*)(dh + ob) = h0;
  *(f16x8*)(dh + ob + 8) = h1;
  if (LO) {
    *(f16x8*)(dl + ob) = l0;
    *(f16x8*)(dl + ob + 8) = l1;
  }
}

// ---------- LayerNorm -> f16 split (+optional fused f32 gate softmax) ----------
template<bool GATE>
__launch_bounds__(256)
__global__ void ln_k(const float* __restrict__ x, const float* __restrict__ g, const float* __restrict__ b,
                     f16* __restrict__ oh, f16* __restrict__ ol,
                     const float* __restrict__ gw, float* __restrict__ gates) {
  int row = blockIdx.x, tid = threadIdx.x;
  int lane = tid & 63, wid = tid >> 6;
  __shared__ float red[4];
  __shared__ float pg[4][8];
  __shared__ float logits[8];
  const float* xr = x + (long)row * DD;
  int col = tid * 4;
  float4 v = *(const float4*)(xr + col);
  float s = v.x + v.y + v.z + v.w;
  #pragma unroll
  for (int off = 32; off >= 1; off >>= 1) s += __shfl_down(s, off);
  if (lane == 0) red[wid] = s;
  __syncthreads();
  float mu = (red[0] + red[1] + red[2] + red[3]) * (1.0f / DD);
  float d0 = v.x - mu, d1 = v.y - mu, d2 = v.z - mu, d3 = v.w - mu;
  float sq = d0 * d0 + d1 * d1 + d2 * d2 + d3 * d3;
  __syncthreads();
  #pragma unroll
  for (int off = 32; off >= 1; off >>= 1) sq += __shfl_down(sq, off);
  if (lane == 0) red[wid] = sq;
  __syncthreads();
  float var = (red[0] + red[1] + red[2] + red[3]) * (1.0f / DD);
  float rstd = rsqrtf(var + 1e-5f);
  float xv[4];
  xv[0] = d0 * rstd * g[col] + b[col];
  xv[1] = d1 * rstd * g[col + 1] + b[col + 1];
  xv[2] = d2 * rstd * g[col + 2] + b[col + 2];
  xv[3] = d3 * rstd * g[col + 3] + b[col + 3];
  f16x4 hv, lv;
  #pragma unroll
  for (int j = 0; j < 4; ++j) { f16 h, lo; split2(xv[j], h, lo); hv[j] = h; lv[j] = lo; }
  *(f16x4*)(oh + (long)row * DD + col) = hv;
  *(f16x4*)(ol + (long)row * DD + col) = lv;
  if (GATE) {
    float part[8];
    #pragma unroll
    for (int e = 0; e < 8; ++e) part[e] = 0.0f;
    #pragma unroll
    for (int j = 0; j < 4; ++j) {
      const float* gwr = gw + (long)(col + j) * 8;
      #pragma unroll
      for (int e = 0; e < 8; ++e) part[e] += xv[j] * gwr[e];
    }
    #pragma unroll
    for (int off = 32; off >= 1; off >>= 1) {
      #pragma unroll
      for (int e = 0; e < 8; ++e) part[e] += __shfl_down(part[e], off);
    }
    if (lane == 0) {
      #pragma unroll
      for (int e = 0; e < 8; ++e) pg[wid][e] = part[e];
    }
    __syncthreads();
    if (tid < 8) logits[tid] = pg[0][tid] + pg[1][tid] + pg[2][tid] + pg[3][tid];
    __syncthreads();
    if (tid < 8) {
      float mx = logits[0];
      #pragma unroll
      for (int e2 = 1; e2 < 8; ++e2) mx = fmaxf(mx, logits[e2]);
      float den = 0.0f;
      #pragma unroll
      for (int e2 = 0; e2 < 8; ++e2) den += expf(logits[e2] - mx);
      gates[(long)row * 8 + tid] = expf(logits[tid] - mx) / den;
    }
  }
}

// ---------- rope tables ----------
__global__ void sincos_k(float* st, float* ct) {
  int i = blockIdx.x * 256 + threadIdx.x;
  if (i >= TT * 32) return;
  int t = i >> 5, f = i & 31;
  float inv = powf(10000.0f, -(float)f * (1.0f / 32.0f));
  float ang = (float)t * inv;
  st[i] = sinf(ang);
  ct[i] = cosf(ang);
}

// ---------- flash attention v2 (REVERT to R3 staged version): 128 q-rows/block ----------
// 4 waves x 32 q-rows. K/V hi/lo staged cooperatively via global_load_lds
// (linear dest + pre-swizzled source); all frag reads XOR-swizzled (slot ^= row&7).
__launch_bounds__(256, 2)
__global__ void attn_k(const f16* __restrict__ qh, const f16* __restrict__ ql,
                       const f16* __restrict__ kh, const f16* __restrict__ kl,
                       const f16* __restrict__ vth, const f16* __restrict__ vtl,
                       f16* __restrict__ oh_out, f16* __restrict__ ol_out) {
  __shared__ __align__(16) f16 KsH[4096], KsL[4096], VsH[4096], VsL[4096];
  __shared__ __align__(16) f16 Pw[4][2][2048];  // [wave][hi/lo][32*64]
  int bx = blockIdx.x;
  int bh = bx & 63;
  int qt = (int)((0x31204657u >> ((bx >> 6) << 2)) & 7u);  // pair big+small qt per CU
  int tid = threadIdx.x;
  int wid = tid >> 6, lane = tid & 63;
  int lr = lane & 15, lg = lane >> 4;
  long bhT = (long)bh * TT;
  int qrow0 = qt * 128 + wid * 32;
  int qend = qrow0 + 32;

  f16x8 qfh[2][2], qfl[2][2];
  #pragma unroll
  for (int qi = 0; qi < 2; ++qi) {
    long qoff = (bhT + qrow0 + qi * 16 + lr) * 64 + lg * 8;
    qfh[qi][0] = *(const f16x8*)(qh + qoff);
    qfh[qi][1] = *(const f16x8*)(qh + qoff + 32);
    qfl[qi][0] = *(const f16x8*)(ql + qoff);
    qfl[qi][1] = *(const f16x8*)(ql + qoff + 32);
  }

  f32x4 o_hi[2][4], o_md[2][4];
  #pragma unroll
  for (int qi = 0; qi < 2; ++qi)
    #pragma unroll
    for (int dj = 0; dj < 4; ++dj) {
      o_hi[qi][dj] = {0.f, 0.f, 0.f, 0.f};
      o_md[qi][dj] = {0.f, 0.f, 0.f, 0.f};
    }
  float m[2][4], lsum[2][4];
  #pragma unroll
  for (int qi = 0; qi < 2; ++qi)
    #pragma unroll
    for (int r = 0; r < 4; ++r) { m[qi][r] = -1e30f; lsum[qi][r] = 0.0f; }

  int srow = tid >> 3, slot = tid & 7;
  int gc = ((slot ^ (srow & 7)) << 3);
  const f16* kHp = kh + (bhT + srow) * 64 + gc;
  const f16* kLp = kl + (bhT + srow) * 64 + gc;
  const f16* vHp = vth + ((long)bh * 64 + srow) * TT + gc;
  const f16* vLp = vtl + ((long)bh * 64 + srow) * TT + gc;
  int t8 = tid * 8;
  int rsw = lr & 7;
  int c0 = ((lg ^ rsw) << 3), c1 = (((4 | lg) ^ rsw) << 3);
  f16* Ph = Pw[wid][0];
  f16* Pl = Pw[wid][1];

  int ntiles = 2 * (qt + 1);
  for (int kb = 0; kb < ntiles; ++kb) {
    int kv0 = kb * 64;
    gload16(kHp + (long)kv0 * 64, KsH + t8);
    gload16(kHp + (long)(kv0 + 32) * 64, KsH + 2048 + t8);
    gload16(kLp + (long)kv0 * 64, KsL + t8);
    gload16(kLp + (long)(kv0 + 32) * 64, KsL + 2048 + t8);
    gload16(vHp + kv0, VsH + t8);
    gload16(vHp + (long)32 * TT + kv0, VsH + 2048 + t8);
    gload16(vLp + kv0, VsL + t8);
    gload16(vLp + (long)32 * TT + kv0, VsL + 2048 + t8);
    __syncthreads();

    if (kv0 < qend) {
      f32x4 s[2][4];
      #pragma unroll
      for (int kj = 0; kj < 4; ++kj) {
        int rb = (kj * 16 + lr) * 64;
        f16x8 kfh0 = *(const f16x8*)(KsH + rb + c0);
        f16x8 kfh1 = *(const f16x8*)(KsH + rb + c1);
        f16x8 kfl0 = *(const f16x8*)(KsL + rb + c0);
        f16x8 kfl1 = *(const f16x8*)(KsL + rb + c1);
        #pragma unroll
        for (int qi = 0; qi < 2; ++qi) {
          f32x4 a = {0.f, 0.f, 0.f, 0.f};
          a = MFMA16(qfh[qi][0], kfh0, a);
          a = MFMA16(qfh[qi][1], kfh1, a);
          a = a * 2048.0f;
          a = MFMA16(qfh[qi][0], kfl0, a);
          a = MFMA16(qfh[qi][1], kfl1, a);
          a = MFMA16(qfl[qi][0], kfh0, a);
          a = MFMA16(qfl[qi][1], kfh1, a);
          s[qi][kj] = a;
        }
      }
      const float ss = 0.125f / 2048.0f;
      bool needmask = (kv0 + 64 > qrow0);
      float rm[2][4];
      #pragma unroll
      for (int qi = 0; qi < 2; ++qi)
        #pragma unroll
        for (int r = 0; r < 4; ++r) {
          int qrow = qrow0 + qi * 16 + lg * 4 + r;
          float mx = -1e30f;
          #pragma unroll
          for (int kj = 0; kj < 4; ++kj) {
            float v = s[qi][kj][r] * ss;
            if (needmask && (kv0 + kj * 16 + lr > qrow)) v = -1e9f;
            s[qi][kj][r] = v;
            mx = fmaxf(mx, v);
          }
          rm[qi][r] = mx;
        }
      #pragma unroll
      for (int off = 1; off < 16; off <<= 1)
        #pragma unroll
        for (int qi = 0; qi < 2; ++qi)
          #pragma unroll
          for (int r = 0; r < 4; ++r) rm[qi][r] = fmaxf(rm[qi][r], __shfl_xor(rm[qi][r], off));
      float alpha[2][4], rs[2][4];
      #pragma unroll
      for (int qi = 0; qi < 2; ++qi)
        #pragma unroll
        for (int r = 0; r < 4; ++r) {
          float mn = fmaxf(m[qi][r], rm[qi][r]);
          alpha[qi][r] = __expf(m[qi][r] - mn);
          m[qi][r] = mn;
          rs[qi][r] = 0.0f;
        }
      #pragma unroll
      for (int qi = 0; qi < 2; ++qi)
        #pragma unroll
        for (int kj = 0; kj < 4; ++kj)
          #pragma unroll
          for (int r = 0; r < 4; ++r) {
            float p = __expf(s[qi][kj][r] - m[qi][r]);
            rs[qi][r] += p;
            int prow = qi * 16 + lg * 4 + r;
            int pcol = kj * 16 + lr;
            int idx = prow * 64 + (((pcol >> 3) ^ (prow & 7)) << 3) + (pcol & 7);
            f16 hv = (f16)p;
            Ph[idx] = hv;
            Pl[idx] = (f16)((p - (float)hv) * 2048.0f);
          }
      #pragma unroll
      for (int off = 1; off < 16; off <<= 1)
        #pragma unroll
        for (int qi = 0; qi < 2; ++qi)
          #pragma unroll
          for (int r = 0; r < 4; ++r) rs[qi][r] += __shfl_xor(rs[qi][r], off);
      #pragma unroll
      for (int qi = 0; qi < 2; ++qi)
        #pragma unroll
        for (int r = 0; r < 4; ++r) lsum[qi][r] = lsum[qi][r] * alpha[qi][r] + rs[qi][r];
      #pragma unroll
      for (int qi = 0; qi < 2; ++qi)
        #pragma unroll
        for (int dj = 0; dj < 4; ++dj)
          #pragma unroll
          for (int r = 0; r < 4; ++r) {
            o_hi[qi][dj][r] *= alpha[qi][r];
            o_md[qi][dj][r] *= alpha[qi][r];
          }
      f16x8 pah[2][2], pal[2][2];
      #pragma unroll
      for (int qi = 0; qi < 2; ++qi) {
        int pr = (qi * 16 + lr) * 64;
        pah[qi][0] = *(const f16x8*)(Ph + pr + c0);
        pah[qi][1] = *(const f16x8*)(Ph + pr + c1);
        pal[qi][0] = *(const f16x8*)(Pl + pr + c0);
        pal[qi][1] = *(const f16x8*)(Pl + pr + c1);
      }
      #pragma unroll
      for (int dj = 0; dj < 4; ++dj) {
        int vb = (dj * 16 + lr) * 64;
        f16x8 vh0 = *(const f16x8*)(VsH + vb + c0);
        f16x8 vh1 = *(const f16x8*)(VsH + vb + c1);
        f16x8 vl0 = *(const f16x8*)(VsL + vb + c0);
        f16x8 vl1 = *(const f16x8*)(VsL + vb + c1);
        #pragma unroll
        for (int qi = 0; qi < 2; ++qi) {
          o_hi[qi][dj] = MFMA16(pah[qi][0], vh0, o_hi[qi][dj]);
          o_hi[qi][dj] = MFMA16(pah[qi][1], vh1, o_hi[qi][dj]);
          o_md[qi][dj] = MFMA16(pah[qi][0], vl0, o_md[qi][dj]);
          o_md[qi][dj] = MFMA16(pah[qi][1], vl1, o_md[qi][dj]);
          o_md[qi][dj] = MFMA16(pal[qi][0], vh0, o_md[qi][dj]);
          o_md[qi][dj] = MFMA16(pal[qi][1], vh1, o_md[qi][dj]);
        }
      }
    }
    __syncthreads();
  }

  int b = bh >> 4, hh = bh & 15;
  #pragma unroll
  for (int qi = 0; qi < 2; ++qi)
    #pragma unroll
    for (int r = 0; r < 4; ++r) {
      float invl = 1.0f / lsum[qi][r];
      int qrow = qrow0 + qi * 16 + lg * 4 + r;
      long obase = ((long)(b * TT + qrow)) * DD + hh * 64 + lr;
      #pragma unroll
      for (int dj = 0; dj < 4; ++dj) {
        float val = (o_hi[qi][dj][r] + o_md[qi][dj][r] * (1.0f / 2048.0f)) * invl;
        f16 hv = (f16)val;
        oh_out[obase + dj * 16] = hv;
        ol_out[obase + dj * 16] = (f16)((val - (float)hv) * 2048.0f);
      }
    }
}

// ---------- fused split-2 f16 GEMM: one K-loop (R3 structure) + XCD-aware grid ----------
// smode 0: 3D grid (bn,bm,z). smode 1: 1D grid, id&7 = expert(z)=XCD, 8x8 supertiles.
// smode 2: 1D grid, bijective chunked XCD swizzle (z=0), 8x8 supertiles, needs M%1024==0.
// EPI 0: outF=v. 1: outF=v+resid. 2: split(gelu(v+bias))->outH/L. 3: outF=v+bias.
// EPI 4: fused qkv rope epilogue: resid=sin table, bias=cos table; q->(q4h,q4l),
//        k->(k4h,k4l) at (b,h,t,64); v->(outH,outL) transposed (b,h,64,t).
template<int EPI, bool SPLIT>
__launch_bounds__(256, 2)
__global__ void gemmF(const f16* __restrict__ Ah, const f16* __restrict__ Al, long sA,
                      const f16* __restrict__ Bh, const f16* __restrict__ Bl, long sB,
                      int M, int N, int K, int smode,
                      float* __restrict__ outF, long sOutF,
                      const float* __restrict__ resid,
                      const float* __restrict__ bias, long sBias,
                      f16* __restrict__ outH, f16* __restrict__ outL, long sOutH,
                      f16* __restrict__ q4h, f16* __restrict__ q4l,
                      f16* __restrict__ k4h, f16* __restrict__ k4l) {
  __shared__ __align__(16) f16 pool[(SPLIT ? 4 : 2) * 128 * 64];
  f16* AsH = pool;
  f16* BsH = pool + 8192;
  f16* AsL = SPLIT ? pool + 16384 : pool;
  f16* BsL = SPLIT ? pool + 24576 : pool;

  int bm, bn, z;
  if (smode == 0) {
    bn = blockIdx.x; bm = blockIdx.y; z = blockIdx.z;
  } else {
    int id = blockIdx.x;
    int logical;
    if (smode == 1) { z = id & 7; logical = id >> 3; }
    else { z = 0; int cpx = (int)(gridDim.x >> 3); logical = (id & 7) * cpx + (id >> 3); }
    int st = logical >> 6, wi = logical & 63;
    int nstm = (smode == 1) ? 1 : (M >> 10);  // supertile rows = M/128/8
    int stm = st % nstm, stn = st / nstm;
    bm = (stm << 3) | (wi & 7);
    bn = (stn << 3) | (wi >> 3);
  }

  int tid = threadIdx.x;
  int wid = tid >> 6, lane = tid & 63;
  int wm = (wid >> 1) * 64, wn = (wid & 1) * 64;
  int lr = lane & 15, lg = lane >> 4;

  f32x4 aH[4][4], aL[4][4];
  #pragma unroll
  for (int i = 0; i < 4; ++i)
    #pragma unroll
    for (int j = 0; j < 4; ++j) {
      aH[i][j] = {0.f, 0.f, 0.f, 0.f};
      if (SPLIT) aL[i][j] = {0.f, 0.f, 0.f, 0.f};
    }

  int srow = tid >> 3;
  int gcol = (((tid & 7) ^ (srow & 7)) << 3);
  const f16* apH = Ah + (long)z * sA + ((long)(bm * 128 + srow)) * K + gcol;
  const f16* bpH = Bh + (long)z * sB + ((long)(bn * 128 + srow)) * K + gcol;
  const f16* apL = nullptr; const f16* bpL = nullptr;
  if (SPLIT) {
    apL = Al + (long)z * sA + ((long)(bm * 128 + srow)) * K + gcol;
    bpL = Bl + (long)z * sB + ((long)(bn * 128 + srow)) * K + gcol;
  }
  int tid8 = tid * 8;
  int rsw = lr & 7;

  for (int kt = 0; kt < K; kt += 64) {
    #pragma unroll
    for (int r4 = 0; r4 < 4; ++r4) {
      long go = (long)kt + (long)(r4 * 32) * K;
      int lo = tid8 + r4 * 2048;
      gload16(apH + go, AsH + lo);
      gload16(bpH + go, BsH + lo);
      if (SPLIT) {
        gload16(apL + go, AsL + lo);
        gload16(bpL + go, BsL + lo);
      }
    }
    __syncthreads();
    #pragma unroll
    for (int kk2 = 0; kk2 < 2; ++kk2) {
      int sws = (((kk2 << 2) | lg) ^ rsw) << 3;
      f16x8 afH[4], afL[4];
      #pragma unroll
      for (int i = 0; i < 4; ++i) {
        int ro = (wm + i * 16 + lr) * 64 + sws;
        afH[i] = *(const f16x8*)(AsH + ro);
        if (SPLIT) afL[i] = *(const f16x8*)(AsL + ro);
      }
      #pragma unroll
      for (int j = 0; j < 4; ++j) {
        int ro = (wn + j * 16 + lr) * 64 + sws;
        f16x8 bH = *(const f16x8*)(BsH + ro);
        #pragma unroll
        for (int i = 0; i < 4; ++i) aH[i][j] = MFMA16(afH[i], bH, aH[i][j]);
        if (SPLIT) {
          f16x8 bL = *(const f16x8*)(BsL + ro);
          #pragma unroll
          for (int i = 0; i < 4; ++i) {
            aL[i][j] = MFMA16(afH[i], bL, aL[i][j]);
            aL[i][j] = MFMA16(afL[i], bH, aL[i][j]);
          }
        }
      }
    }
    __syncthreads();
  }

  if (EPI == 4) {
    int c64 = (bn * 128 + wn) >> 6;
    int type = c64 % 3, hd = c64 / 3;   // 0=q 1=k 2=v
    const float* stab = resid;
    const float* ctab = bias;
    #pragma unroll
    for (int i = 0; i < 4; ++i) {
      #pragma unroll
      for (int r = 0; r < 4; ++r) {
        int row = bm * 128 + wm + i * 16 + lg * 4 + r;
        int b = row >> 10, t = row & (TT - 1);
        long bh = (long)(b * HH + hd);
        if (type == 2) {
          #pragma unroll
          for (int j = 0; j < 4; ++j) {
            float v = aH[i][j][r] + aL[i][j][r] * (1.0f / 2048.0f);
            int d = j * 16 + lr;
            long idx = (bh * 64 + d) * TT + t;
            split_store(outH + idx, outL + idx, v);
          }
        } else {
          f16* oh = (type == 0) ? q4h : k4h;
          f16* ol = (type == 0) ? q4l : k4l;
          long obase = (bh * TT + t) * 64;
          #pragma unroll
          for (int j = 0; j < 2; ++j) {
            int half = j * 16 + lr;
            float sa = stab[t * 32 + half], ca = ctab[t * 32 + half];
            float x1 = aH[i][j][r] + aL[i][j][r] * (1.0f / 2048.0f);
            float x2 = aH[i][j + 2][r] + aL[i][j + 2][r] * (1.0f / 2048.0f);
            split_store(oh + obase + half, ol + obase + half, x1 * ca - x2 * sa);
            split_store(oh + obase + half + 32, ol + obase + half + 32, x1 * sa + x2 * ca);
          }
        }
      }
    }
    return;
  }

  #pragma unroll
  for (int i = 0; i < 4; ++i) {
    #pragma unroll
    for (int j = 0; j < 4; ++j) {
      #pragma unroll
      for (int r = 0; r < 4; ++r) {
        int row = bm * 128 + wm + i * 16 + lg * 4 + r;
        int col = bn * 128 + wn + j * 16 + lr;
        float v = aH[i][j][r];
        if (SPLIT) v += aL[i][j][r] * (1.0f / 2048.0f);
        if (EPI == 0) {
          outF[(long)row * N + col] = v;
        } else if (EPI == 1) {
          long idx = (long)row * N + col;
          outF[idx] = v + resid[idx];
        } else if (EPI == 2) {
          float t = v + bias[(long)z * sBias + col];
          float ge = 0.5f * t * (1.0f + erff(t * 0.70710678118f));
          long idx = (long)z * sOutH + (long)row * N + col;
          f16 hv = (f16)ge;
          outH[idx] = hv;
          if (SPLIT) outL[idx] = (f16)((ge - (float)hv) * 2048.0f);
        } else {
          long idx = (long)z * sOutF + (long)row * N + col;
          outF[idx] = v + bias[(long)z * sBias + col];
        }
      }
    }
  }
}

// ---------- routing: top-2 + per-expert capacity scan (exact ref semantics) ----------
__launch_bounds__(512)
__global__ void route_k(const float* __restrict__ gates, int* __restrict__ etok, int* __restrict__ slotof) {
  __shared__ unsigned char lmask[NTOK];
  __shared__ unsigned char ltop[NTOK];
  int tid = threadIdx.x;
  for (int t = tid; t < NTOK; t += 512) {
    const float* gr = gates + (long)t * 8;
    float gv[8];
    #pragma unroll
    for (int e = 0; e < 8; ++e) gv[e] = gr[e];
    int e1 = 0; float bv = gv[0];
    #pragma unroll
    for (int e = 1; e < 8; ++e) if (gv[e] > bv) { bv = gv[e]; e1 = e; }
    int e2 = -1; float bv2 = -1e30f;
    #pragma unroll
    for (int e = 0; e < 8; ++e) if (e != e1 && gv[e] > bv2) { bv2 = gv[e]; e2 = e; }
    lmask[t] = (unsigned char)((1u << e1) | (1u << e2));
    ltop[t] = (unsigned char)(e1 | (e2 << 4));
    slotof[t * 2] = -1;
    slotof[t * 2 + 1] = -1;
  }
  __syncthreads();
  int e = tid >> 6, lane = tid & 63;
  int cnt = 0;
  for (int c = 0; c < NTOK / 64; ++c) {
    int t = c * 64 + lane;
    int bit = (lmask[t] >> e) & 1;
    unsigned long long bal = __ballot(bit);
    int pre = __popcll(bal & ((1ull << lane) - 1ull));
    int slot = cnt + pre;
    if (bit && slot < CAPS) {
      etok[e * CAPS + slot] = t;
      int tp = ltop[t];
      int k = ((tp & 15) == e) ? 0 : 1;
      slotof[t * 2 + k] = (e << 16) | slot;
    }
    cnt += __popcll(bal);
  }
  int kept = cnt < CAPS ? cnt : CAPS;
  for (int s = kept + lane; s < CAPS; s += 64) etok[e * CAPS + s] = 0;
}

// ---------- gather rows for experts ----------
__global__ void gather_k(const int* __restrict__ etok, const f16* __restrict__ xh, const f16* __restrict__ xl,
                         f16* __restrict__ gh, f16* __restrict__ gl) {
  int es = blockIdx.x, tid = threadIdx.x;  // 128 threads
  int tok = etok[es];
  const uint4* s1 = (const uint4*)(xh + (long)tok * DD);
  const uint4* s2 = (const uint4*)(xl + (long)tok * DD);
  ((uint4*)(gh + (long)es * DD))[tid] = s1[tid];
  ((uint4*)(gl + (long)es * DD))[tid] = s2[tid];
}

// ---------- scatter expert outputs back (x += sum gv * out), no atomics ----------
__global__ void scatter_k(const int* __restrict__ slotof, const float* __restrict__ gates,
                          const float* __restrict__ moe, float* __restrict__ x) {
  int t = blockIdx.x, tid = threadIdx.x;  // 256 threads
  int s0 = slotof[t * 2], s1 = slotof[t * 2 + 1];
  float4* xr = (float4*)(x + (long)t * DD);
  float4 v = xr[tid];
  if (s0 >= 0) {
    int e = s0 >> 16, sl = s0 & 0xffff;
    float gv = gates[(long)t * 8 + e];
    float4 mo = ((const float4*)(moe + ((long)e * CAPS + sl) * DD))[tid];
    v.x += gv * mo.x; v.y += gv * mo.y; v.z += gv * mo.z; v.w += gv * mo.w;
  }
  if (s1 >= 0) {
    int e = s1 >> 16, sl = s1 & 0xffff;
    float gv = gates[(long)t * 8 + e];
    float4 mo = ((const float4*)(moe + ((long)e * CAPS + sl) * DD))[tid];
    v.x += gv * mo.x; v.y += gv * mo.y; v.z += gv * mo.z; v.w += gv * mo.w;
  }
  xr[tid] = v;
}

extern "C" void kernel_launch(void* const* d_in, const int* in_sizes, int n_in,
                              void* d_out, int out_size, void* d_ws, size_t ws_size,
                              hipStream_t stream) {
  const float* x_in   = (const float*)d_in[0];
  const float* ln1_g  = (const float*)d_in[1];
  const float* ln1_b  = (const float*)d_in[2];
  const float* qkv_w  = (const float*)d_in[3];
  const float* proj_w = (const float*)d_in[4];
  const float* ln2_g  = (const float*)d_in[5];
  const float* ln2_b  = (const float*)d_in[6];
  const float* gate_w = (const float*)d_in[7];
  const float* w1     = (const float*)d_in[8];
  const float* b1     = (const float*)d_in[9];
  const float* w2     = (const float*)d_in[10];
  const float* b2     = (const float*)d_in[11];
  float* x = (float*)d_out;

  char* p = (char*)d_ws;
  auto alloc = [&](size_t bytes) { char* r = p; p += (bytes + 255) & ~(size_t)255; return (void*)r; };

  f16* Wreg   = (f16*)alloc(134217728);           // weight split region (reused)
  f16* qhB  = (f16*)alloc(4194304ull * 2);
  f16* qlB  = (f16*)alloc(4194304ull * 2);
  f16* khB  = (f16*)alloc(4194304ull * 2);
  f16* klB  = (f16*)alloc(4194304ull * 2);
  f16* vthB = (f16*)alloc(4194304ull * 2);
  f16* vtlB = (f16*)alloc(4194304ull * 2);
  f16* xnh  = (f16*)alloc(4194304ull * 2);
  f16* xnl  = (f16*)alloc(4194304ull * 2);
  f16* atth = (f16*)alloc(4194304ull * 2);
  f16* attl = (f16*)alloc(4194304ull * 2);
  f16* xgh  = (f16*)alloc(8388608ull * 2);
  f16* xgl  = (f16*)alloc(8388608ull * 2);
  f16* hhB  = (f16*)alloc(33554432ull * 2);
  f16* hlB  = (f16*)alloc(33554432ull * 2);
  float* moe = (float*)alloc(8388608ull * 4);
  float* stab = (float*)alloc(32768ull * 4);
  float* ctab = (float*)alloc(32768ull * 4);
  float* gates = (float*)alloc(32768ull * 4);
  int* etok  = (int*)alloc(8192ull * 4);
  int* slotof = (int*)alloc(8192ull * 4);

  f16* qkvTh = Wreg;
  f16* qkvTl = Wreg + 3145728;
  f16* projTh = Wreg + 2 * 3145728;
  f16* projTl = Wreg + 2 * 3145728 + 1048576;
  f16* w1Th = Wreg;
  f16* w1Tl = Wreg + 33554432;
  f16* w2Th = Wreg;
  f16* w2Tl = Wreg + 33554432;

  hipMemcpyAsync(x, x_in, (size_t)NTOK * DD * 4, hipMemcpyDeviceToDevice, stream);
  sincos_k<<<(TT * 32 + 255) / 256, 256, 0, stream>>>(stab, ctab);

  for (int l = 0; l < 2; ++l) {
    // --- attention half ---
    splitT_k<true><<<dim3(3072 / 64, 1024 / 64, 1), 256, 0, stream>>>(
        qkv_w + (long)l * DD * 3072, qkvTh, qkvTl, 1024, 3072, 0, 0);
    splitT_k<true><<<dim3(1024 / 64, 1024 / 64, 1), 256, 0, stream>>>(
        proj_w + (long)l * DD * DD, projTh, projTl, 1024, 1024, 0, 0);
    ln_k<false><<<NTOK, 256, 0, stream>>>(x, ln1_g + l * DD, ln1_b + l * DD, xnh, xnl, nullptr, nullptr);
    gemmF<4, true><<<768, 256, 0, stream>>>(                     // fused qkv+rope, smode 2
        xnh, xnl, 0, qkvTh, qkvTl, 0, 4096, 3072, 1024, 2,
        nullptr, 0, stab, ctab, 0, vthB, vtlB, 0, qhB, qlB, khB, klB);
    attn_k<<<512, 256, 0, stream>>>(qhB, qlB, khB, klB, vthB, vtlB, atth, attl);
    gemmF<1, true><<<256, 256, 0, stream>>>(                     // smode 2 chunked
        atth, attl, 0, projTh, projTl, 0, 4096, 1024, 1024, 2,
        x, 0, x, nullptr, 0, nullptr, nullptr, 0, nullptr, nullptr, nullptr, nullptr);

    // --- MoE half ---
    ln_k<true><<<NTOK, 256, 0, stream>>>(x, ln2_g + l * DD, ln2_b + l * DD, xnh, xnl,
                                         gate_w + (long)l * DD * EE, gates);
    route_k<<<1, 512, 0, stream>>>(gates, etok, slotof);
    gather_k<<<EE * CAPS, 128, 0, stream>>>(etok, xnh, xnl, xgh, xgl);
    if (l == 0) {
      splitT_k<true><<<dim3(4096 / 64, 1024 / 64, EE), 256, 0, stream>>>(
          w1 + (long)l * EE * DD * 4096, w1Th, w1Tl, 1024, 4096, (long)DD * 4096, (long)4096 * DD);
      gemmF<2, true><<<2048, 256, 0, stream>>>(                  // smode 1 expert->XCD
          xgh, xgl, (long)CAPS * DD, w1Th, w1Tl, (long)4096 * DD, 1024, 4096, 1024, 1,
          nullptr, 0, nullptr, b1 + (long)l * EE * 4096, 4096, hhB, hlB, (long)CAPS * 4096,
          nullptr, nullptr, nullptr, nullptr);
      splitT_k<true><<<dim3(1024 / 64, 4096 / 64, EE), 256, 0, stream>>>(
          w2 + (long)l * EE * 4096 * DD, w2Th, w2Tl, 4096, 1024, (long)4096 * DD, (long)DD * 4096);
      gemmF<3, true><<<512, 256, 0, stream>>>(                   // smode 1 expert->XCD
          hhB, hlB, (long)CAPS * 4096, w2Th, w2Tl, (long)DD * 4096, 1024, 1024, 4096, 1,
          moe, (long)CAPS * DD, nullptr, b2 + (long)l * EE * DD, DD, nullptr, nullptr, 0,
          nullptr, nullptr, nullptr, nullptr);
    } else {
      splitT_k<false><<<dim3(4096 / 64, 1024 / 64, EE), 256, 0, stream>>>(
          w1 + (long)l * EE * DD * 4096, w1Th, w1Tl, 1024, 4096, (long)DD * 4096, (long)4096 * DD);
      gemmF<2, false><<<2048, 256, 0, stream>>>(
          xgh, xgl, (long)CAPS * DD, w1Th, w1Tl, (long)4096 * DD, 1024, 4096, 1024, 1,
          nullptr, 0, nullptr, b1 + (long)l * EE * 4096, 4096, hhB, hlB, (long)CAPS * 4096,
          nullptr, nullptr, nullptr, nullptr);
      splitT_k<false><<<dim3(1024 / 64, 4096 / 64, EE), 256, 0, stream>>>(
          w2 + (long)l * EE * 4096 * DD, w2Th, w2Tl, 4096, 1024, (long)4096 * DD, (long)DD * 4096);
      gemmF<3, false><<<512, 256, 0, stream>>>(
          hhB, hlB, (long)CAPS * 4096, w2Th, w2Tl, (long)DD * 4096, 1024, 1024, 4096, 1,
          moe, (long)CAPS * DD, nullptr, b2 + (long)l * EE * DD, DD, nullptr, nullptr, 0,
          nullptr, nullptr, nullptr, nullptr);
    }
    scatter_k<<<NTOK, 256, 0, stream>>>(slotof, gates, moe, x);
  }
  (void)in_sizes; (void)n_in; (void)out_size; (void)ws_size;
}